// Round 10
// baseline (194.722 us; speedup 1.0000x reference)
//
#include <hip/hip_runtime.h>

// Causal MHSA: B=2, T=2048, C=1024, H=16, Dh=64.
// prep -> QKV GEMM -> flash attn (S^T orientation) -> out GEMM.
//
// R10: GEMMs get the attn-style software pipeline: double-buffered BK=32
// tiles, stage(c+1) issued AFTER the barrier while computing chunk c ->
// global->LDS latency hidden behind MFMA (R8/R9 staged then immediately
// drained at the next barrier). Conflict-free LDS via fat-row layout:
// two 32-elem K-rows packed per 128B LDS row, phys granule =
// ((mrow&1)*4 + kq) ^ (fatrow&7), swizzle applied on the GLOBAL side of
// global_load_lds (R9 proved 0 conflicts with this family). BK=32 keeps
// VGPR ~<=104 and 32 KB LDS (grid is 3 blocks/CU anyway). attn/prep frozen.

typedef __bf16 bf16;
typedef __attribute__((ext_vector_type(4))) __bf16 bf16x4;
typedef __attribute__((ext_vector_type(8))) __bf16 bf16x8;
typedef __attribute__((ext_vector_type(4))) float f32x4;

#define T_SEQ 2048
#define NHEAD 16
#define QSCALE 0.1803368801111244f  // log2(e)/sqrt(64)

__device__ __forceinline__ void async16(const bf16* g, const bf16* l) {
    __builtin_amdgcn_global_load_lds(
        (const __attribute__((address_space(1))) void*)g,
        (__attribute__((address_space(3))) void*)l, 16, 0, 0);
}

// ---------------- fused prep ----------------
__global__ __launch_bounds__(256) void prep(
    const float* __restrict__ x, bf16* __restrict__ xb,
    const float* __restrict__ qkv_w, bf16* __restrict__ wbT,
    const float* __restrict__ out_w, bf16* __restrict__ owbT) {
    const int bid = blockIdx.x, tid = threadIdx.x;
    if (bid < 4096) {
        int i = (bid * 256 + tid) * 4;
        float4 v = *(const float4*)(x + i);
        bf16x4 o;
        o.x = (bf16)v.x; o.y = (bf16)v.y; o.z = (bf16)v.z; o.w = (bf16)v.w;
        *(bf16x4*)(xb + i) = o;
        return;
    }
    __shared__ float tile[32][33];
    const float* in;
    bf16* out;
    int K_, N_, b;
    if (bid < 7168) { b = bid - 4096; in = qkv_w; out = wbT; K_ = 1024; N_ = 3072; }
    else            { b = bid - 7168; in = out_w; out = owbT; K_ = 1024; N_ = 1024; }
    int k0 = (b & 31) * 32, n0 = (b >> 5) * 32;
    int tx = tid & 31, ty = tid >> 5;
    for (int r = 0; r < 32; r += 8)
        tile[ty + r][tx] = in[(k0 + ty + r) * N_ + n0 + tx];
    __syncthreads();
    for (int r = 0; r < 32; r += 8)
        out[(n0 + ty + r) * K_ + k0 + tx] = (bf16)tile[tx][ty + r];
}

// Fat-row tile helpers (tile: R rows x 32 k-elems, stored as R/2 fat rows of
// 64 elems). Staging round covers 256 granules (32 fat rows) per 256 threads.
//   granule G (0..R*4-1): fat = G>>3, phys p = G&7, logical lg = p ^ (fat&7),
//   mrow = fat*2 + (lg>>2), kgran = lg&3.
// Frag read (m-subtile row = base + l15, k-gran = quad):
//   fat = (base + l15)>>1 = base/2 + (l15>>1); phys = ((l15&1)*4+quad)^(l15>>1)

// ---------------- GEMM 1: qkv = x @ qkv_w + b, scatter to Q/K/Vt ----------------
// 128x128 tile, BK=32, double-buffered, pipelined.
__global__ __launch_bounds__(256) void gemm_qkv(
    const bf16* __restrict__ A, const bf16* __restrict__ Bt,
    const float* __restrict__ bias,
    bf16* __restrict__ Qo, bf16* __restrict__ Ko, bf16* __restrict__ Vt) {
    __shared__ __align__(16) bf16 As[2][128 * 32];
    __shared__ __align__(16) bf16 Bs[2][128 * 32];
    const int t = threadIdx.x;
    const int lane = t & 63, wave = t >> 6;
    const int l15 = lane & 15, quad = lane >> 4;
    const int wm = wave & 1, wn = wave >> 1;
    const int m0 = blockIdx.y * 128, n0 = blockIdx.x * 128;
    const int sec = n0 >> 10;  // block-uniform: 0=Q, 1=K, 2=V

    f32x4 acc[4][4] = {};

    // staging address pieces (independent of k0 / round except mrow offset)
    const int sfat = t >> 3, sp = t & 7;
    const int slg = sp ^ (sfat & 7);
    const int smrow = sfat * 2 + (slg >> 2);   // 0..63 (+64 for round 1)
    const int skoff = (slg & 3) << 3;          // 0,8,16,24
    const bf16* ag = A + (m0 + smrow) * 1024 + skoff;
    const bf16* bg = Bt + (n0 + smrow) * 1024 + skoff;
    const int ldst = wave * 512;               // + round*2048 elems

    auto stage = [&](int k0, int b) {
        async16(ag + k0, &As[b][ldst]);
        async16(ag + 64 * 1024 + k0, &As[b][2048 + ldst]);
        async16(bg + k0, &Bs[b][ldst]);
        async16(bg + 64 * 1024 + k0, &Bs[b][2048 + ldst]);
    };

    // frag-read offsets
    const int ffat = l15 >> 1;                                  // + base/2
    const int fphys = (((l15 & 1) << 2) | quad) ^ (l15 >> 1);   // granule
    const int foff = ffat * 64 + fphys * 8;                     // elem offset

    stage(0, 0);
    for (int c = 0; c < 32; c++) {
        __syncthreads();              // stage(c) landed (had compute(c-1) to fly)
        if (c + 1 < 32) stage((c + 1) * 32, (c + 1) & 1);
        const bf16* asb = &As[c & 1][0];
        const bf16* bsb = &Bs[c & 1][0];
        bf16x8 af[4], bfr[4];
        for (int i = 0; i < 4; i++)
            af[i] = *(const bf16x8*)(asb + (wm * 64 + i * 16) * 32 + foff);
        for (int j = 0; j < 4; j++)
            bfr[j] = *(const bf16x8*)(bsb + (wn * 64 + j * 16) * 32 + foff);
        if (sec < 2) {
            for (int j = 0; j < 4; j++)
                for (int i = 0; i < 4; i++)
                    acc[j][i] = __builtin_amdgcn_mfma_f32_16x16x32_bf16(bfr[j], af[i], acc[j][i], 0, 0, 0);
        } else {
            for (int i = 0; i < 4; i++)
                for (int j = 0; j < 4; j++)
                    acc[i][j] = __builtin_amdgcn_mfma_f32_16x16x32_bf16(af[i], bfr[j], acc[i][j], 0, 0, 0);
        }
    }

    if (sec < 2) {
        bf16* dst = (sec == 0) ? Qo : Ko;
        const float sc = (sec == 0) ? QSCALE : 1.0f;
        for (int j = 0; j < 4; j++) {
            int col0 = n0 + wn * 64 + j * 16 + quad * 4;  // 4 consecutive feats
            float4 bv = *(const float4*)(bias + col0);
            int c2 = col0 & 1023, h = c2 >> 6, d0 = c2 & 63;
            for (int i = 0; i < 4; i++) {
                int row = m0 + wm * 64 + i * 16 + l15;
                int b = row >> 11, tt = row & 2047;
                int bh = b * NHEAD + h;
                bf16x4 o;
                o[0] = (bf16)((acc[j][i][0] + bv.x) * sc);
                o[1] = (bf16)((acc[j][i][1] + bv.y) * sc);
                o[2] = (bf16)((acc[j][i][2] + bv.z) * sc);
                o[3] = (bf16)((acc[j][i][3] + bv.w) * sc);
                *(bf16x4*)(dst + (bh * T_SEQ + tt) * 64 + d0) = o;
            }
        }
    } else {
        for (int j = 0; j < 4; j++) {
            int col = n0 + wn * 64 + j * 16 + l15;
            float bv = bias[col];
            int c2 = col & 1023, h = c2 >> 6, d = c2 & 63;
            for (int i = 0; i < 4; i++) {
                int row0 = m0 + wm * 64 + i * 16 + quad * 4;  // 4 consecutive t
                int b = row0 >> 11, tt0 = row0 & 2047;
                int bh = b * NHEAD + h;
                bf16x4 o;
                for (int r = 0; r < 4; r++)
                    o[r] = (bf16)(acc[i][j][r] + bv);
                *(bf16x4*)(Vt + (bh * 64 + d) * T_SEQ + tt0) = o;
            }
        }
    }
}

// ---------------- attention (R7, unchanged) ----------------
#define PST 80
__global__ __launch_bounds__(256, 4) void attn(
    const bf16* __restrict__ Q, const bf16* __restrict__ K,
    const bf16* __restrict__ Vt, bf16* __restrict__ AO) {
    __shared__ __align__(16) bf16 Ks[2][64 * 64];
    __shared__ __align__(16) bf16 Vs[2][64 * 64];
    __shared__ __align__(16) bf16 Pa[4][16 * PST];
    const int tid = threadIdx.x;
    const int lane = tid & 63, wave = tid >> 6;
    const int l15 = lane & 15, quad = lane >> 4;
    const int xcdr = blockIdx.x & 7;
    const int i_ = blockIdx.x >> 3;
    const int bh = (xcdr << 2) | (i_ & 3);
    const int ti = i_ >> 2;
    const int qt = (ti & 1) ? (ti >> 1) : (31 - (ti >> 1));
    const int t0w = qt * 64 + wave * 16;

    const bf16* kp = K + bh * T_SEQ * 64;
    const bf16* vp = Vt + bh * 64 * T_SEQ;
    bf16* pw = &Pa[wave][0];
    const int b_ = bh >> 4, h_ = bh & 15;

    const int sx = (quad ^ (l15 & 7)) << 3;

    const bf16* qp = Q + (bh * T_SEQ + t0w) * 64;
    bf16x8 qf0 = *(const bf16x8*)(qp + l15 * 64 + quad * 8);
    bf16x8 qf1 = *(const bf16x8*)(qp + l15 * 64 + 32 + quad * 8);

    auto stage = [&](int kb, int b) {
        for (int i = 0; i < 2; i++) {
            int row = i * 32 + (tid >> 3), p = tid & 7;
            const bf16* ksrc = kp + (kb + row) * 64 + ((p ^ (row & 7)) << 3);
            async16(ksrc, &Ks[b][i * 2048 + wave * 512]);
            const bf16* vsrc = vp + row * T_SEQ + kb + ((p ^ (row & 7)) << 3);
            async16(vsrc, &Vs[b][i * 2048 + wave * 512]);
        }
    };

    f32x4 acc[4] = {};
    float lsum = 0.0f;

    const int C = qt + 1;
    stage(0, 0);
    for (int c = 0; c < C; c++) {
        __syncthreads();
        if (c + 1 < C) stage((c + 1) * 64, (c + 1) & 1);
        const bf16* ksb = &Ks[c & 1][0];
        const bf16* vsb = &Vs[c & 1][0];
        const bool dg = (c == qt);
        const int na = dg ? (wave + 1) : 4;

        f32x4 sc[4];
        for (int n = 0; n < 4; n++) {
            if (n < na) {
                const bf16* kbase = ksb + (n * 16 + l15) * 64;
                bf16x8 kf0 = *(const bf16x8*)(kbase + sx);
                bf16x8 kf1 = *(const bf16x8*)(kbase + (sx ^ 32));
                f32x4 z = {};
                z = __builtin_amdgcn_mfma_f32_16x16x32_bf16(kf0, qf0, z, 0, 0, 0);
                z = __builtin_amdgcn_mfma_f32_16x16x32_bf16(kf1, qf1, z, 0, 0, 0);
                sc[n] = z;
            }
        }
        for (int n = 0; n < 4; n++) {
            bf16x4 pv;
            if (n < na) {
                const bool dmask = dg && (n == na - 1);
                for (int r = 0; r < 4; r++) {
                    float v = sc[n][r];
                    if (dmask && (quad * 4 + r > l15)) v = -100000.0f;
                    float e = __builtin_amdgcn_exp2f(v);
                    lsum += e;
                    pv[r] = (bf16)e;
                }
            } else {
                pv[0] = pv[1] = pv[2] = pv[3] = (bf16)0.0f;
            }
            *(bf16x4*)(pw + l15 * PST + n * 16 + quad * 4) = pv;
        }
        __builtin_amdgcn_s_waitcnt(0xC07F);
        for (int g = 0; g < 2; g++) {
            bf16x8 pf = *(const bf16x8*)(pw + l15 * PST + g * 32 + quad * 8);
            for (int j = 0; j < 4; j++) {
                const bf16* vbase = vsb + (j * 16 + l15) * 64;
                bf16x8 vf = *(const bf16x8*)(vbase + (g ? (sx ^ 32) : sx));
                acc[j] = __builtin_amdgcn_mfma_f32_16x16x32_bf16(pf, vf, acc[j], 0, 0, 0);
            }
        }
    }

    lsum += __shfl_xor(lsum, 16);
    lsum += __shfl_xor(lsum, 32);
    float linv = 1.0f / lsum;

    bf16* aop = AO + (b_ * T_SEQ + t0w) * 1024 + h_ * 64;
    for (int r = 0; r < 4; r++) {
        float lr = __shfl(linv, quad * 4 + r, 16);
        for (int j = 0; j < 4; j++)
            aop[(quad * 4 + r) * 1024 + j * 16 + l15] = (bf16)(acc[j][r] * lr);
    }
}

// ---------------- GEMM 2: out = AO @ out_w + out_b (fp32 out) ----------------
// 64x128 tile, BK=32, double-buffered, pipelined. 512 blocks (2/CU). C^T.
__global__ __launch_bounds__(256) void gemm_out_k(
    const bf16* __restrict__ A, const bf16* __restrict__ Bt,
    const float* __restrict__ bias, float* __restrict__ out) {
    __shared__ __align__(16) bf16 As[2][64 * 32];
    __shared__ __align__(16) bf16 Bs[2][128 * 32];
    const int t = threadIdx.x;
    const int lane = t & 63, wave = t >> 6;
    const int l15 = lane & 15, quad = lane >> 4;
    const int wm = wave & 1, wn = wave >> 1;
    const int m0 = blockIdx.y * 64, n0 = blockIdx.x * 128;

    f32x4 acc[4][2] = {};  // acc[j][i]: C^T (row=feature, col=t)

    const int sfat = t >> 3, sp = t & 7;
    const int slg = sp ^ (sfat & 7);
    const int smrow = sfat * 2 + (slg >> 2);
    const int skoff = (slg & 3) << 3;
    const bf16* ag = A + (m0 + smrow) * 1024 + skoff;
    const bf16* bg = Bt + (n0 + smrow) * 1024 + skoff;
    const int ldst = wave * 512;

    auto stage = [&](int k0, int b) {
        async16(ag + k0, &As[b][ldst]);
        async16(bg + k0, &Bs[b][ldst]);
        async16(bg + 64 * 1024 + k0, &Bs[b][2048 + ldst]);
    };

    const int foff = (l15 >> 1) * 64 + ((((l15 & 1) << 2) | quad) ^ (l15 >> 1)) * 8;

    stage(0, 0);
    for (int c = 0; c < 32; c++) {
        __syncthreads();
        if (c + 1 < 32) stage((c + 1) * 32, (c + 1) & 1);
        const bf16* asb = &As[c & 1][0];
        const bf16* bsb = &Bs[c & 1][0];
        bf16x8 af[2], bfr[4];
        for (int i = 0; i < 2; i++)
            af[i] = *(const bf16x8*)(asb + (wm * 32 + i * 16) * 32 + foff);
        for (int j = 0; j < 4; j++)
            bfr[j] = *(const bf16x8*)(bsb + (wn * 64 + j * 16) * 32 + foff);
        for (int j = 0; j < 4; j++)
            for (int i = 0; i < 2; i++)
                acc[j][i] = __builtin_amdgcn_mfma_f32_16x16x32_bf16(bfr[j], af[i], acc[j][i], 0, 0, 0);
    }

    for (int j = 0; j < 4; j++) {
        int col0 = n0 + wn * 64 + j * 16 + quad * 4;
        float4 bv = *(const float4*)(bias + col0);
        for (int i = 0; i < 2; i++) {
            int row = m0 + wm * 32 + i * 16 + l15;
            float4 o;
            o.x = acc[j][i][0] + bv.x;
            o.y = acc[j][i][1] + bv.y;
            o.z = acc[j][i][2] + bv.z;
            o.w = acc[j][i][3] + bv.w;
            *(float4*)(out + row * 1024 + col0) = o;
        }
    }
}

// ---------------- launch ----------------
extern "C" void kernel_launch(void* const* d_in, const int* in_sizes, int n_in,
                              void* d_out, int out_size, void* d_ws, size_t ws_size,
                              hipStream_t stream) {
    const float* x     = (const float*)d_in[0];
    const float* qkv_w = (const float*)d_in[1];
    const float* qkv_b = (const float*)d_in[2];
    const float* out_w = (const float*)d_in[3];
    const float* out_b = (const float*)d_in[4];
    float* out = (float*)d_out;

    char* ws = (char*)d_ws;
    bf16* xb   = (bf16*)(ws);                     // 8 MB
    bf16* wbT  = (bf16*)(ws + (8ull << 20));      // 6 MB
    bf16* owbT = (bf16*)(ws + (14ull << 20));     // 2 MB
    bf16* Qb   = (bf16*)(ws + (16ull << 20));     // 8 MB (B,H,T,Dh), pre-scaled
    bf16* Kb   = (bf16*)(ws + (24ull << 20));     // 8 MB (B,H,T,Dh)
    bf16* Vt   = (bf16*)(ws + (32ull << 20));     // 8 MB (B,H,Dh,T)
    bf16* AO   = (bf16*)(ws + (40ull << 20));     // 8 MB (B,T,C)

    prep<<<8192, 256, 0, stream>>>(x, xb, qkv_w, wbT, out_w, owbT);
    gemm_qkv<<<dim3(24, 32), 256, 0, stream>>>(xb, wbT, qkv_b, Qb, Kb, Vt);
    attn<<<1024, 256, 0, stream>>>(Qb, Kb, Vt, AO);
    gemm_out_k<<<dim3(8, 64), 256, 0, stream>>>(AO, owbT, out_b, out);
}

// Round 11
// 174.585 us; speedup vs baseline: 1.1153x; 1.1153x over previous
//
#include <hip/hip_runtime.h>

// Causal MHSA: B=2, T=2048, C=1024, H=16, Dh=64.
// prep -> QKV GEMM -> flash attn (S^T orientation) -> out GEMM.
//
// R11 = R8 structure (single-buffer BK=32, two barriers, branch outside
// K-loop, VGPR ~80 — fastest GEMM so far) + the R9/R10-verified fat-row
// XOR-swizzled LDS addressing (0 bank conflicts, correctness-proven R10).
// R9 (BK=64) and R10 (single-barrier dbuf pipeline) both regressed: VGPR
// 116 / VALU bloat — the 2-barrier BK=32 shape is the local optimum
// (matches guide m99-m141: source-level pipelining doesn't beat it).
// Layout: tile stored as 64 fat rows x 64 elems (2 m-rows per fat row);
// phys granule = logical ^ (fat&7), swizzle applied on the GLOBAL address
// side of global_load_lds. Frag reads: 16 lanes hit each granule exactly
// 2x -> 2-way = free (m136). attn/prep frozen.

typedef __bf16 bf16;
typedef __attribute__((ext_vector_type(4))) __bf16 bf16x4;
typedef __attribute__((ext_vector_type(8))) __bf16 bf16x8;
typedef __attribute__((ext_vector_type(4))) float f32x4;

#define T_SEQ 2048
#define NHEAD 16
#define QSCALE 0.1803368801111244f  // log2(e)/sqrt(64)

__device__ __forceinline__ void async16(const bf16* g, const bf16* l) {
    __builtin_amdgcn_global_load_lds(
        (const __attribute__((address_space(1))) void*)g,
        (__attribute__((address_space(3))) void*)l, 16, 0, 0);
}

// ---------------- fused prep ----------------
__global__ __launch_bounds__(256) void prep(
    const float* __restrict__ x, bf16* __restrict__ xb,
    const float* __restrict__ qkv_w, bf16* __restrict__ wbT,
    const float* __restrict__ out_w, bf16* __restrict__ owbT) {
    const int bid = blockIdx.x, tid = threadIdx.x;
    if (bid < 4096) {
        int i = (bid * 256 + tid) * 4;
        float4 v = *(const float4*)(x + i);
        bf16x4 o;
        o.x = (bf16)v.x; o.y = (bf16)v.y; o.z = (bf16)v.z; o.w = (bf16)v.w;
        *(bf16x4*)(xb + i) = o;
        return;
    }
    __shared__ float tile[32][33];
    const float* in;
    bf16* out;
    int K_, N_, b;
    if (bid < 7168) { b = bid - 4096; in = qkv_w; out = wbT; K_ = 1024; N_ = 3072; }
    else            { b = bid - 7168; in = out_w; out = owbT; K_ = 1024; N_ = 1024; }
    int k0 = (b & 31) * 32, n0 = (b >> 5) * 32;
    int tx = tid & 31, ty = tid >> 5;
    for (int r = 0; r < 32; r += 8)
        tile[ty + r][tx] = in[(k0 + ty + r) * N_ + n0 + tx];
    __syncthreads();
    for (int r = 0; r < 32; r += 8)
        out[(n0 + ty + r) * K_ + k0 + tx] = (bf16)tile[tx][ty + r];
}

// ---------------- GEMM 1: qkv = x @ qkv_w + b, scatter to Q/K/Vt ----------------
// 128x128 tile, BK=32, single-buffer two-barrier (R8), fat-row swizzled LDS.
__global__ __launch_bounds__(256) void gemm_qkv(
    const bf16* __restrict__ A, const bf16* __restrict__ Bt,
    const float* __restrict__ bias,
    bf16* __restrict__ Qo, bf16* __restrict__ Ko, bf16* __restrict__ Vt) {
    __shared__ __align__(16) bf16 As[128 * 32];
    __shared__ __align__(16) bf16 Bs[128 * 32];
    const int t = threadIdx.x;
    const int lane = t & 63, wave = t >> 6;
    const int l15 = lane & 15, quad = lane >> 4;
    const int wm = wave & 1, wn = wave >> 1;
    const int m0 = blockIdx.y * 128, n0 = blockIdx.x * 128;
    const int sec = n0 >> 10;  // block-uniform: 0=Q, 1=K, 2=V

    f32x4 acc[4][4] = {};

    // fat-row staging: thread t -> phys granule t (LDS elems t*8), source
    // fat row sfat=t>>3, logical granule slg = (t&7)^(sfat&7):
    // m-row = sfat*2 + (slg>>2), k-offset = (slg&3)*8
    const int sfat = t >> 3, sp = t & 7;
    const int slg = sp ^ (sfat & 7);
    const int smrow = sfat * 2 + (slg >> 2);
    const int skoff = (slg & 3) << 3;
    const bf16* ag = A + (m0 + smrow) * 1024 + skoff;
    const bf16* bg = Bt + (n0 + smrow) * 1024 + skoff;
    bf16* as0 = As + wave * 512;
    bf16* as1 = As + 2048 + wave * 512;
    bf16* bs0 = Bs + wave * 512;
    bf16* bs1 = Bs + 2048 + wave * 512;

    // frag read: row base+l15 -> fat (base/2 + (l15>>1)), phys granule
    // (((l15&1)*4)|quad) ^ (l15>>1); (base*32 + foff) == fat*64 + phys*8
    const int foff = (l15 >> 1) * 64 + (((((l15 & 1) << 2) | quad)) ^ (l15 >> 1)) * 8;

    if (sec < 2) {
        // swapped orientation: acc[j][i] = C^T (row=feature, col=t)
        for (int k0 = 0; k0 < 1024; k0 += 32) {
            async16(ag + k0, as0);
            async16(ag + 64 * 1024 + k0, as1);
            async16(bg + k0, bs0);
            async16(bg + 64 * 1024 + k0, bs1);
            __syncthreads();
            bf16x8 af[4], bfr[4];
            for (int i = 0; i < 4; i++)
                af[i] = *(const bf16x8*)(As + (wm * 64 + i * 16) * 32 + foff);
            for (int j = 0; j < 4; j++)
                bfr[j] = *(const bf16x8*)(Bs + (wn * 64 + j * 16) * 32 + foff);
            for (int j = 0; j < 4; j++)
                for (int i = 0; i < 4; i++)
                    acc[j][i] = __builtin_amdgcn_mfma_f32_16x16x32_bf16(bfr[j], af[i], acc[j][i], 0, 0, 0);
            __syncthreads();
        }
        bf16* dst = (sec == 0) ? Qo : Ko;
        const float sc = (sec == 0) ? QSCALE : 1.0f;
        for (int j = 0; j < 4; j++) {
            int col0 = n0 + wn * 64 + j * 16 + quad * 4;  // 4 consecutive feats
            float4 bv = *(const float4*)(bias + col0);
            int c2 = col0 & 1023, h = c2 >> 6, d0 = c2 & 63;
            for (int i = 0; i < 4; i++) {
                int row = m0 + wm * 64 + i * 16 + l15;
                int b = row >> 11, tt = row & 2047;
                int bh = b * NHEAD + h;
                bf16x4 o;
                o[0] = (bf16)((acc[j][i][0] + bv.x) * sc);
                o[1] = (bf16)((acc[j][i][1] + bv.y) * sc);
                o[2] = (bf16)((acc[j][i][2] + bv.z) * sc);
                o[3] = (bf16)((acc[j][i][3] + bv.w) * sc);
                *(bf16x4*)(dst + (bh * T_SEQ + tt) * 64 + d0) = o;
            }
        }
    } else {
        // normal orientation: acc[i][j] (row=t, col=feature) -> Vt
        for (int k0 = 0; k0 < 1024; k0 += 32) {
            async16(ag + k0, as0);
            async16(ag + 64 * 1024 + k0, as1);
            async16(bg + k0, bs0);
            async16(bg + 64 * 1024 + k0, bs1);
            __syncthreads();
            bf16x8 af[4], bfr[4];
            for (int i = 0; i < 4; i++)
                af[i] = *(const bf16x8*)(As + (wm * 64 + i * 16) * 32 + foff);
            for (int j = 0; j < 4; j++)
                bfr[j] = *(const bf16x8*)(Bs + (wn * 64 + j * 16) * 32 + foff);
            for (int i = 0; i < 4; i++)
                for (int j = 0; j < 4; j++)
                    acc[i][j] = __builtin_amdgcn_mfma_f32_16x16x32_bf16(af[i], bfr[j], acc[i][j], 0, 0, 0);
            __syncthreads();
        }
        for (int j = 0; j < 4; j++) {
            int col = n0 + wn * 64 + j * 16 + l15;
            float bv = bias[col];
            int c2 = col & 1023, h = c2 >> 6, d = c2 & 63;
            for (int i = 0; i < 4; i++) {
                int row0 = m0 + wm * 64 + i * 16 + quad * 4;  // 4 consecutive t
                int b = row0 >> 11, tt0 = row0 & 2047;
                int bh = b * NHEAD + h;
                bf16x4 o;
                for (int r = 0; r < 4; r++)
                    o[r] = (bf16)(acc[i][j][r] + bv);
                *(bf16x4*)(Vt + (bh * 64 + d) * T_SEQ + tt0) = o;
            }
        }
    }
}

// ---------------- attention (R7, unchanged) ----------------
#define PST 80
__global__ __launch_bounds__(256, 4) void attn(
    const bf16* __restrict__ Q, const bf16* __restrict__ K,
    const bf16* __restrict__ Vt, bf16* __restrict__ AO) {
    __shared__ __align__(16) bf16 Ks[2][64 * 64];
    __shared__ __align__(16) bf16 Vs[2][64 * 64];
    __shared__ __align__(16) bf16 Pa[4][16 * PST];
    const int tid = threadIdx.x;
    const int lane = tid & 63, wave = tid >> 6;
    const int l15 = lane & 15, quad = lane >> 4;
    const int xcdr = blockIdx.x & 7;
    const int i_ = blockIdx.x >> 3;
    const int bh = (xcdr << 2) | (i_ & 3);
    const int ti = i_ >> 2;
    const int qt = (ti & 1) ? (ti >> 1) : (31 - (ti >> 1));
    const int t0w = qt * 64 + wave * 16;

    const bf16* kp = K + bh * T_SEQ * 64;
    const bf16* vp = Vt + bh * 64 * T_SEQ;
    bf16* pw = &Pa[wave][0];
    const int b_ = bh >> 4, h_ = bh & 15;

    const int sx = (quad ^ (l15 & 7)) << 3;

    const bf16* qp = Q + (bh * T_SEQ + t0w) * 64;
    bf16x8 qf0 = *(const bf16x8*)(qp + l15 * 64 + quad * 8);
    bf16x8 qf1 = *(const bf16x8*)(qp + l15 * 64 + 32 + quad * 8);

    auto stage = [&](int kb, int b) {
        for (int i = 0; i < 2; i++) {
            int row = i * 32 + (tid >> 3), p = tid & 7;
            const bf16* ksrc = kp + (kb + row) * 64 + ((p ^ (row & 7)) << 3);
            async16(ksrc, &Ks[b][i * 2048 + wave * 512]);
            const bf16* vsrc = vp + row * T_SEQ + kb + ((p ^ (row & 7)) << 3);
            async16(vsrc, &Vs[b][i * 2048 + wave * 512]);
        }
    };

    f32x4 acc[4] = {};
    float lsum = 0.0f;

    const int C = qt + 1;
    stage(0, 0);
    for (int c = 0; c < C; c++) {
        __syncthreads();
        if (c + 1 < C) stage((c + 1) * 64, (c + 1) & 1);
        const bf16* ksb = &Ks[c & 1][0];
        const bf16* vsb = &Vs[c & 1][0];
        const bool dg = (c == qt);
        const int na = dg ? (wave + 1) : 4;

        f32x4 sc[4];
        for (int n = 0; n < 4; n++) {
            if (n < na) {
                const bf16* kbase = ksb + (n * 16 + l15) * 64;
                bf16x8 kf0 = *(const bf16x8*)(kbase + sx);
                bf16x8 kf1 = *(const bf16x8*)(kbase + (sx ^ 32));
                f32x4 z = {};
                z = __builtin_amdgcn_mfma_f32_16x16x32_bf16(kf0, qf0, z, 0, 0, 0);
                z = __builtin_amdgcn_mfma_f32_16x16x32_bf16(kf1, qf1, z, 0, 0, 0);
                sc[n] = z;
            }
        }
        for (int n = 0; n < 4; n++) {
            bf16x4 pv;
            if (n < na) {
                const bool dmask = dg && (n == na - 1);
                for (int r = 0; r < 4; r++) {
                    float v = sc[n][r];
                    if (dmask && (quad * 4 + r > l15)) v = -100000.0f;
                    float e = __builtin_amdgcn_exp2f(v);
                    lsum += e;
                    pv[r] = (bf16)e;
                }
            } else {
                pv[0] = pv[1] = pv[2] = pv[3] = (bf16)0.0f;
            }
            *(bf16x4*)(pw + l15 * PST + n * 16 + quad * 4) = pv;
        }
        __builtin_amdgcn_s_waitcnt(0xC07F);
        for (int g = 0; g < 2; g++) {
            bf16x8 pf = *(const bf16x8*)(pw + l15 * PST + g * 32 + quad * 8);
            for (int j = 0; j < 4; j++) {
                const bf16* vbase = vsb + (j * 16 + l15) * 64;
                bf16x8 vf = *(const bf16x8*)(vbase + (g ? (sx ^ 32) : sx));
                acc[j] = __builtin_amdgcn_mfma_f32_16x16x32_bf16(pf, vf, acc[j], 0, 0, 0);
            }
        }
    }

    lsum += __shfl_xor(lsum, 16);
    lsum += __shfl_xor(lsum, 32);
    float linv = 1.0f / lsum;

    bf16* aop = AO + (b_ * T_SEQ + t0w) * 1024 + h_ * 64;
    for (int r = 0; r < 4; r++) {
        float lr = __shfl(linv, quad * 4 + r, 16);
        for (int j = 0; j < 4; j++)
            aop[(quad * 4 + r) * 1024 + j * 16 + l15] = (bf16)(acc[j][r] * lr);
    }
}

// ---------------- GEMM 2: out = AO @ out_w + out_b (fp32 out) ----------------
// 64x128 tile, BK=32, single-buffer two-barrier, fat-row swizzled LDS.
// 512 blocks (2/CU). C^T orientation -> float4 stores.
__global__ __launch_bounds__(256) void gemm_out_k(
    const bf16* __restrict__ A, const bf16* __restrict__ Bt,
    const float* __restrict__ bias, float* __restrict__ out) {
    __shared__ __align__(16) bf16 As[64 * 32];
    __shared__ __align__(16) bf16 Bs[128 * 32];
    const int t = threadIdx.x;
    const int lane = t & 63, wave = t >> 6;
    const int l15 = lane & 15, quad = lane >> 4;
    const int wm = wave & 1, wn = wave >> 1;
    const int m0 = blockIdx.y * 64, n0 = blockIdx.x * 128;

    f32x4 acc[4][2] = {};  // acc[j][i]: C^T (row=feature, col=t)

    const int sfat = t >> 3, sp = t & 7;
    const int slg = sp ^ (sfat & 7);
    const int smrow = sfat * 2 + (slg >> 2);
    const int skoff = (slg & 3) << 3;
    const bf16* ag = A + (m0 + smrow) * 1024 + skoff;
    const bf16* bg = Bt + (n0 + smrow) * 1024 + skoff;
    bf16* as0 = As + wave * 512;
    bf16* bs0 = Bs + wave * 512;
    bf16* bs1 = Bs + 2048 + wave * 512;

    const int foff = (l15 >> 1) * 64 + (((((l15 & 1) << 2) | quad)) ^ (l15 >> 1)) * 8;

    for (int k0 = 0; k0 < 1024; k0 += 32) {
        async16(ag + k0, as0);
        async16(bg + k0, bs0);
        async16(bg + 64 * 1024 + k0, bs1);
        __syncthreads();
        bf16x8 af[2], bfr[4];
        for (int i = 0; i < 2; i++)
            af[i] = *(const bf16x8*)(As + (wm * 32 + i * 16) * 32 + foff);
        for (int j = 0; j < 4; j++)
            bfr[j] = *(const bf16x8*)(Bs + (wn * 64 + j * 16) * 32 + foff);
        for (int j = 0; j < 4; j++)
            for (int i = 0; i < 2; i++)
                acc[j][i] = __builtin_amdgcn_mfma_f32_16x16x32_bf16(bfr[j], af[i], acc[j][i], 0, 0, 0);
        __syncthreads();
    }

    for (int j = 0; j < 4; j++) {
        int col0 = n0 + wn * 64 + j * 16 + quad * 4;
        float4 bv = *(const float4*)(bias + col0);
        for (int i = 0; i < 2; i++) {
            int row = m0 + wm * 32 + i * 16 + l15;
            float4 o;
            o.x = acc[j][i][0] + bv.x;
            o.y = acc[j][i][1] + bv.y;
            o.z = acc[j][i][2] + bv.z;
            o.w = acc[j][i][3] + bv.w;
            *(float4*)(out + row * 1024 + col0) = o;
        }
    }
}

// ---------------- launch ----------------
extern "C" void kernel_launch(void* const* d_in, const int* in_sizes, int n_in,
                              void* d_out, int out_size, void* d_ws, size_t ws_size,
                              hipStream_t stream) {
    const float* x     = (const float*)d_in[0];
    const float* qkv_w = (const float*)d_in[1];
    const float* qkv_b = (const float*)d_in[2];
    const float* out_w = (const float*)d_in[3];
    const float* out_b = (const float*)d_in[4];
    float* out = (float*)d_out;

    char* ws = (char*)d_ws;
    bf16* xb   = (bf16*)(ws);                     // 8 MB
    bf16* wbT  = (bf16*)(ws + (8ull << 20));      // 6 MB
    bf16* owbT = (bf16*)(ws + (14ull << 20));     // 2 MB
    bf16* Qb   = (bf16*)(ws + (16ull << 20));     // 8 MB (B,H,T,Dh), pre-scaled
    bf16* Kb   = (bf16*)(ws + (24ull << 20));     // 8 MB (B,H,T,Dh)
    bf16* Vt   = (bf16*)(ws + (32ull << 20));     // 8 MB (B,H,Dh,T)
    bf16* AO   = (bf16*)(ws + (40ull << 20));     // 8 MB (B,T,C)

    prep<<<8192, 256, 0, stream>>>(x, xb, qkv_w, wbT, out_w, owbT);
    gemm_qkv<<<dim3(24, 32), 256, 0, stream>>>(xb, wbT, qkv_b, Qb, Kb, Vt);
    attn<<<1024, 256, 0, stream>>>(Qb, Kb, Vt, AO);
    gemm_out_k<<<dim3(8, 64), 256, 0, stream>>>(AO, owbT, out_b, out);
}